// Round 8
// baseline (237.529 us; speedup 1.0000x reference)
//
#include <hip/hip_runtime.h>
#include <hip/hip_bf16.h>
#include <stdint.h>
#include <stddef.h>

typedef __hip_bfloat16 bf16;
typedef __attribute__((ext_vector_type(8))) short short8;   // 8 bf16 = 4 VGPRs
typedef __attribute__((ext_vector_type(4))) float floatx4;  // MFMA 16x16 accumulator

// async global->LDS, 16 B per lane. LDS dest must be wave-uniform base + lane*16.
__device__ __forceinline__ void async_load16(const bf16* g, bf16* l) {
#if defined(__has_builtin) && __has_builtin(__builtin_amdgcn_global_load_lds)
  __builtin_amdgcn_global_load_lds((__attribute__((address_space(1))) void*)g,
                                   (__attribute__((address_space(3))) void*)l,
                                   16, 0, 0);
#else
  *(short8*)l = *(const short8*)g;
#endif
}

// ---------------------------------------------------------------------------
// Wave-local input dtype detection (f32 vs bf16) — verified round 7.
// ---------------------------------------------------------------------------
__device__ __forceinline__ int wave_detect_f32(const unsigned short* __restrict__ xr) {
  const int lane = threadIdx.x & 63;
  const unsigned short u = xr[lane];
  const int e = (u >> 7) & 0xFF;
  const unsigned long long m = __ballot(e >= 0x93);
  return (__popcll(m) > 5) ? 1 : 0;
}

__device__ __forceinline__ float ldf(const void* p, int i, int flg) {
  return flg ? ((const float*)p)[i] : __bfloat162float(((const bf16*)p)[i]);
}

// ---------------------------------------------------------------------------
// Fused prep: all canonicalization + three Weff builds, one dispatch.
// ---------------------------------------------------------------------------
struct PrepArgs {
  const void *x, *ft, *bq, *bf, *bp;
  const void *Wq, *Aq, *Bq, *Wf, *Af, *Bf, *Wp, *Ap, *Bp;
  bf16 *cx, *cft, *cbq, *cbf, *cbp, *weffq, *wefff, *weffp;
};

__device__ __forceinline__ void canon4(const void* src, bf16* dst, int i4, int flg) {
  if (flg) {
    const float4 v = ((const float4*)src)[i4];
    dst[i4 * 4 + 0] = __float2bfloat16(v.x);
    dst[i4 * 4 + 1] = __float2bfloat16(v.y);
    dst[i4 * 4 + 2] = __float2bfloat16(v.z);
    dst[i4 * 4 + 3] = __float2bfloat16(v.w);
  } else {
    ((uint2*)dst)[i4] = ((const uint2*)src)[i4];
  }
}

__device__ __forceinline__ void weff1(const void* W, const void* Bm, const void* Am,
                                      bf16* dst, int idx, int flg) {
  const int n = idx >> 10, k = idx & 1023;
  float acc = 0.f;
#pragma unroll
  for (int r = 0; r < 16; ++r)
    acc += ldf(Bm, n * 16 + r, flg) * ldf(Am, r * 1024 + k, flg);
  dst[idx] = __float2bfloat16(ldf(W, idx, flg) + 0.0625f * acc);
}

__global__ __launch_bounds__(256) void prep_kernel(PrepArgs a) {
  const int flg = wave_detect_f32((const unsigned short*)a.x);
  const int bid = blockIdx.x, tid = threadIdx.x;
  if (bid < 8192) {
    canon4(a.x, a.cx, bid * 256 + tid, flg);
  } else if (bid < 10240) {
    canon4(a.ft, a.cft, (bid - 8192) * 256 + tid, flg);
  } else if (bid < 10241) {
    canon4(a.bq, a.cbq, tid, flg);
  } else if (bid < 10243) {
    canon4(a.bf, a.cbf, (bid - 10241) * 256 + tid, flg);
  } else if (bid < 10244) {
    canon4(a.bp, a.cbp, tid, flg);
  } else if (bid < 14340) {
    weff1(a.Wq, a.Bq, a.Aq, a.weffq, (bid - 10244) * 256 + tid, flg);
  } else if (bid < 22532) {
    weff1(a.Wf, a.Bf, a.Af, a.wefff, (bid - 14340) * 256 + tid, flg);
  } else {
    weff1(a.Wp, a.Bp, a.Ap, a.weffp, (bid - 22532) * 256 + tid, flg);
  }
}

// ---------------------------------------------------------------------------
// Fused q-proj + kv-proj GEMM, 768 blocks, XCD-swizzled (verified round 6).
// NEW round 8: double-buffered LDS, prefetch distance 1, ONE barrier/iter:
//   prologue load buf0; iter: sync -> issue loads buf^1 -> MFMA on buf.
// Next-iter loads overlap the MFMA phase; barrier drain pays only residual.
// ---------------------------------------------------------------------------
__global__ __launch_bounds__(256) void gemm_qkv(
    const bf16* __restrict__ cx, const bf16* __restrict__ cft,
    const bf16* __restrict__ weffq, const bf16* __restrict__ wefff,
    const bf16* __restrict__ cbq, const bf16* __restrict__ cbf,
    bf16* __restrict__ qws, bf16* __restrict__ kws, bf16* __restrict__ vtws) {
  __shared__ __align__(16) bf16 sA[2][128 * 32];
  __shared__ __align__(16) bf16 sB[2][128 * 32];
  const int bid = blockIdx.x, tid = threadIdx.x;
  const int K = 1024;
  int mode, bm, bn;
  const bf16 *A, *Bt, *bias;
  if (bid < 512) {
    mode = 0; A = cx; Bt = weffq; bias = cbq;
    bm = (((bid & 7) << 3) | ((bid >> 3) & 7)) * 128;
    bn = (bid >> 6) * 128;
  } else {
    const int b2 = bid - 512;
    mode = 1; A = cft; Bt = wefff; bias = cbf;
    bm = (((b2 & 7) << 1) | ((b2 >> 3) & 1)) * 128;
    bn = (b2 >> 4) * 128;
  }
  const int srow = tid >> 2, scol = (tid & 3) << 3;
  const bf16* ga0 = A + (size_t)(bm + srow) * K + scol;
  const bf16* ga1 = ga0 + (size_t)64 * K;
  const bf16* gb0 = Bt + (size_t)(bn + srow) * K + scol;
  const bf16* gb1 = gb0 + (size_t)64 * K;
  const int wave = tid >> 6, lane = tid & 63;
  const int wm = (wave >> 1) << 6, wn = (wave & 1) << 6;
  const int lrow = lane & 15, quad = lane >> 4;

  const floatx4 zero4 = {0.f, 0.f, 0.f, 0.f};
  floatx4 acc[4][4];
#pragma unroll
  for (int i = 0; i < 4; ++i)
#pragma unroll
    for (int j = 0; j < 4; ++j) acc[i][j] = zero4;

  // prologue: stage first K-slab into buffer 0
  async_load16(ga0, &sA[0][tid * 8]);
  async_load16(ga1, &sA[0][2048 + tid * 8]);
  async_load16(gb0, &sB[0][tid * 8]);
  async_load16(gb1, &sB[0][2048 + tid * 8]);
  ga0 += 32; ga1 += 32; gb0 += 32; gb1 += 32;

  int cur = 0;
  for (int k0 = 0; k0 < K; k0 += 32) {
    __syncthreads();  // drains vmcnt(0): buf[cur] ready; prior reads done
    if (k0 + 32 < K) {
      const int nxt = cur ^ 1;
      async_load16(ga0, &sA[nxt][tid * 8]);
      async_load16(ga1, &sA[nxt][2048 + tid * 8]);
      async_load16(gb0, &sB[nxt][tid * 8]);
      async_load16(gb1, &sB[nxt][2048 + tid * 8]);
      ga0 += 32; ga1 += 32; gb0 += 32; gb1 += 32;
    }
    short8 af[4], bfr[4];
#pragma unroll
    for (int i = 0; i < 4; ++i) {
      af[i]  = *(const short8*)(&sA[cur][(wm + i * 16 + lrow) * 32 + quad * 8]);
      bfr[i] = *(const short8*)(&sB[cur][(wn + i * 16 + lrow) * 32 + quad * 8]);
    }
#pragma unroll
    for (int i = 0; i < 4; ++i)
#pragma unroll
      for (int j = 0; j < 4; ++j)
        acc[i][j] = __builtin_amdgcn_mfma_f32_16x16x32_bf16(af[i], bfr[j], acc[i][j], 0, 0, 0);
    cur ^= 1;
  }

#pragma unroll
  for (int i = 0; i < 4; ++i) {
    const int mbase = bm + wm + i * 16 + quad * 4;
#pragma unroll
    for (int j = 0; j < 4; ++j) {
      const int n = bn + wn + j * 16 + lrow;
      const float bv = __bfloat162float(bias[n]);
#pragma unroll
      for (int r = 0; r < 4; ++r) {
        const int m = mbase + r;
        const bf16 hval = __float2bfloat16(acc[i][j][r] + bv);
        if (mode == 0) {
          const int b = m >> 10, t = m & 1023, hh = n >> 6, d = n & 63;
          qws[(((size_t)(b * 16 + hh)) * 1024 + t) * 64 + d] = hval;
        } else {
          const int b = m >> 8, s = m & 255;
          if (n < 1024) {
            const int hh = n >> 6, d = n & 63;
            kws[(((size_t)(b * 16 + hh)) * 256 + s) * 64 + d] = hval;
          } else {
            const int nn = n - 1024, hh = nn >> 6, d = nn & 63;
            vtws[(((size_t)(b * 16 + hh)) * 64 + d) * 256 + s] = hval;
          }
        }
      }
    }
  }
}

// ---------------------------------------------------------------------------
// Out-proj GEMM, XCD-swizzled, double-buffered (same structure as gemm_qkv).
// ---------------------------------------------------------------------------
__global__ __launch_bounds__(256) void gemm_out(
    const bf16* __restrict__ A, const bf16* __restrict__ Bt,
    const bf16* __restrict__ bias, void* __restrict__ out0,
    const unsigned short* __restrict__ xraw) {
  __shared__ __align__(16) bf16 sA[2][128 * 32];
  __shared__ __align__(16) bf16 sB[2][128 * 32];
  const int bid = blockIdx.x, tid = threadIdx.x;
  const int K = 1024, N = 1024;
  const int bm = (((bid & 7) << 3) | ((bid >> 3) & 7)) * 128;
  const int bn = (bid >> 6) * 128;
  const int srow = tid >> 2, scol = (tid & 3) << 3;
  const bf16* ga0 = A + (size_t)(bm + srow) * K + scol;
  const bf16* ga1 = ga0 + (size_t)64 * K;
  const bf16* gb0 = Bt + (size_t)(bn + srow) * K + scol;
  const bf16* gb1 = gb0 + (size_t)64 * K;
  const int wave = tid >> 6, lane = tid & 63;
  const int wm = (wave >> 1) << 6, wn = (wave & 1) << 6;
  const int lrow = lane & 15, quad = lane >> 4;

  const floatx4 zero4 = {0.f, 0.f, 0.f, 0.f};
  floatx4 acc[4][4];
#pragma unroll
  for (int i = 0; i < 4; ++i)
#pragma unroll
    for (int j = 0; j < 4; ++j) acc[i][j] = zero4;

  async_load16(ga0, &sA[0][tid * 8]);
  async_load16(ga1, &sA[0][2048 + tid * 8]);
  async_load16(gb0, &sB[0][tid * 8]);
  async_load16(gb1, &sB[0][2048 + tid * 8]);
  ga0 += 32; ga1 += 32; gb0 += 32; gb1 += 32;

  int cur = 0;
  for (int k0 = 0; k0 < K; k0 += 32) {
    __syncthreads();
    if (k0 + 32 < K) {
      const int nxt = cur ^ 1;
      async_load16(ga0, &sA[nxt][tid * 8]);
      async_load16(ga1, &sA[nxt][2048 + tid * 8]);
      async_load16(gb0, &sB[nxt][tid * 8]);
      async_load16(gb1, &sB[nxt][2048 + tid * 8]);
      ga0 += 32; ga1 += 32; gb0 += 32; gb1 += 32;
    }
    short8 af[4], bfr[4];
#pragma unroll
    for (int i = 0; i < 4; ++i) {
      af[i]  = *(const short8*)(&sA[cur][(wm + i * 16 + lrow) * 32 + quad * 8]);
      bfr[i] = *(const short8*)(&sB[cur][(wn + i * 16 + lrow) * 32 + quad * 8]);
    }
#pragma unroll
    for (int i = 0; i < 4; ++i)
#pragma unroll
      for (int j = 0; j < 4; ++j)
        acc[i][j] = __builtin_amdgcn_mfma_f32_16x16x32_bf16(af[i], bfr[j], acc[i][j], 0, 0, 0);
    cur ^= 1;
  }

  const int flg = wave_detect_f32(xraw);
#pragma unroll
  for (int i = 0; i < 4; ++i) {
    const int mbase = bm + wm + i * 16 + quad * 4;
#pragma unroll
    for (int j = 0; j < 4; ++j) {
      const int n = bn + wn + j * 16 + lrow;
      const float bv = __bfloat162float(bias[n]);
#pragma unroll
      for (int r = 0; r < 4; ++r) {
        const int m = mbase + r;
        const float fval = acc[i][j][r] + bv;
        const size_t idx = (size_t)m * N + n;
        if (flg) ((float*)out0)[idx] = fval;
        else     ((bf16*)out0)[idx] = __float2bfloat16(fval);
      }
    }
  }
}

// ---------------------------------------------------------------------------
// Attention: 512 thr / 8 waves, padded LDS, per-wave sP, no max-pass
// (verified rounds 4-7).
// ---------------------------------------------------------------------------
#define SKP 72
#define SVP 264
__global__ __launch_bounds__(512, 2) void attn_kernel(
    const bf16* __restrict__ qws, const bf16* __restrict__ kws,
    const bf16* __restrict__ vtws, bf16* __restrict__ yws) {
  const int b = blockIdx.z, h = blockIdx.y, qc = blockIdx.x;
  const int bh = b * 16 + h;
  __shared__ __align__(16) bf16 sK[256 * SKP];
  __shared__ __align__(16) bf16 sVt[64 * SVP];
  __shared__ __align__(16) bf16 sP[8][16 * SVP];
  const int tid = threadIdx.x, wave = tid >> 6, lane = tid & 63;
  const int lrow = lane & 15, quad = lane >> 4;
  const bf16* kg = kws + (size_t)bh * (256 * 64);
  const bf16* vg = vtws + (size_t)bh * (64 * 256);
#pragma unroll
  for (int i = 0; i < 4; ++i) {
    const int idx = i * 512 + tid;
    const int kr = idx >> 3, kc = (idx & 7) * 8;
    *(short8*)(sK + kr * SKP + kc) = *(const short8*)(kg + kr * 64 + kc);
    const int vr = idx >> 5, vc = (idx & 31) * 8;
    *(short8*)(sVt + vr * SVP + vc) = *(const short8*)(vg + vr * 256 + vc);
  }
  __syncthreads();
  bf16* sPw = sP[wave];
  const floatx4 zero4 = {0.f, 0.f, 0.f, 0.f};
  const float kscale = 0.18033688011112042f;  // (1/8) * log2(e)

  for (int st = 0; st < 4; ++st) {
    const int t0 = qc * 512 + wave * 64 + st * 16;
    const bf16* qrow = qws + ((size_t)bh * 1024 + t0 + lrow) * 64;
    const short8 aq0 = *(const short8*)(qrow + quad * 8);
    const short8 aq1 = *(const short8*)(qrow + 32 + quad * 8);
    floatx4 sc[16];
#pragma unroll
    for (int nt = 0; nt < 16; ++nt) {
      floatx4 c = zero4;
      c = __builtin_amdgcn_mfma_f32_16x16x32_bf16(
          aq0, *(const short8*)(sK + (nt * 16 + lrow) * SKP + quad * 8), c, 0, 0, 0);
      c = __builtin_amdgcn_mfma_f32_16x16x32_bf16(
          aq1, *(const short8*)(sK + (nt * 16 + lrow) * SKP + 32 + quad * 8), c, 0, 0, 0);
      sc[nt] = c;
    }
    float sum[4] = {0.f, 0.f, 0.f, 0.f};
#pragma unroll
    for (int nt = 0; nt < 16; ++nt) {
      const int s = nt * 16 + lrow;
#pragma unroll
      for (int r = 0; r < 4; ++r) {
        const int t = t0 + quad * 4 + r;
        const float p = (s <= t) ? exp2f(sc[nt][r] * kscale) : 0.f;
        sum[r] += p;
        sPw[(quad * 4 + r) * SVP + nt * 16 + lrow] = __float2bfloat16(p);
      }
    }
#pragma unroll
    for (int r = 0; r < 4; ++r) {
      sum[r] += __shfl_xor(sum[r], 1, 16);
      sum[r] += __shfl_xor(sum[r], 2, 16);
      sum[r] += __shfl_xor(sum[r], 4, 16);
      sum[r] += __shfl_xor(sum[r], 8, 16);
    }
    asm volatile("s_waitcnt lgkmcnt(0)" ::: "memory");
    floatx4 ya[4];
#pragma unroll
    for (int nt = 0; nt < 4; ++nt) ya[nt] = zero4;
#pragma unroll
    for (int ks = 0; ks < 8; ++ks) {
      const short8 ap = *(const short8*)(sPw + lrow * SVP + ks * 32 + quad * 8);
#pragma unroll
      for (int nt = 0; nt < 4; ++nt)
        ya[nt] = __builtin_amdgcn_mfma_f32_16x16x32_bf16(
            ap, *(const short8*)(sVt + (nt * 16 + lrow) * SVP + ks * 32 + quad * 8),
            ya[nt], 0, 0, 0);
    }
#pragma unroll
    for (int r = 0; r < 4; ++r) {
      const float rl = 1.f / sum[r];
      const int t = t0 + quad * 4 + r;
#pragma unroll
      for (int nt = 0; nt < 4; ++nt)
        yws[((size_t)b * 1024 + t) * 1024 + h * 64 + nt * 16 + lrow] =
            __float2bfloat16(ya[nt][r] * rl);
    }
  }
}

// ---------------------------------------------------------------------------
extern "C" void kernel_launch(void* const* d_in, const int* in_sizes, int n_in,
                              void* d_out, int out_size, void* d_ws, size_t ws_size,
                              hipStream_t stream) {
  char* p = (char*)d_ws;
  bf16* cbq   = (bf16*)p;     p += 4096;
  bf16* cbf   = (bf16*)p;     p += 8192;
  bf16* cbp   = (bf16*)p;     p += 4096;
  bf16* weffq = (bf16*)p;     p += (size_t)1024 * 1024 * 2;
  bf16* wefff = (bf16*)p;     p += (size_t)2048 * 1024 * 2;
  bf16* weffp = (bf16*)p;     p += (size_t)1024 * 1024 * 2;
  bf16* qws   = (bf16*)p;     p += (size_t)8 * 16 * 1024 * 64 * 2;
  bf16* kws   = (bf16*)p;     p += (size_t)8 * 16 * 256 * 64 * 2;
  bf16* vtws  = (bf16*)p;     p += (size_t)8 * 16 * 64 * 256 * 2;
  bf16* cft   = (bf16*)p;     p += (size_t)8 * 256 * 1024 * 2;
  bf16* cx    = (bf16*)p;     p += (size_t)8 * 1024 * 1024 * 2;
  bf16* yws   = cx;  // disjoint lifetimes: cx dead after q-proj, yws born in attn
  const size_t required = (size_t)(p - (char*)d_ws);
  if (ws_size < required) return;

  PrepArgs pa;
  pa.x = d_in[0]; pa.ft = d_in[1];
  pa.bq = d_in[3]; pa.bf = d_in[7]; pa.bp = d_in[11];
  pa.Wq = d_in[2];  pa.Aq = d_in[4];  pa.Bq = d_in[5];
  pa.Wf = d_in[6];  pa.Af = d_in[8];  pa.Bf = d_in[9];
  pa.Wp = d_in[10]; pa.Ap = d_in[12]; pa.Bp = d_in[13];
  pa.cx = cx; pa.cft = cft; pa.cbq = cbq; pa.cbf = cbf; pa.cbp = cbp;
  pa.weffq = weffq; pa.wefff = wefff; pa.weffp = weffp;
  prep_kernel<<<26628, 256, 0, stream>>>(pa);

  gemm_qkv<<<768, 256, 0, stream>>>(cx, cft, weffq, wefff, cbq, cbf, qws, kws, vtws);
  attn_kernel<<<dim3(2, 16, 8), 512, 0, stream>>>(qws, kws, vtws, yws);
  gemm_out<<<512, 256, 0, stream>>>(yws, weffp, cbp, d_out, (const unsigned short*)d_in[0]);
}